// Round 1
// baseline (744.509 us; speedup 1.0000x reference)
//
#include <hip/hip_runtime.h>
#include <float.h>

#define NN   768
#define CC   1024
#define HIDD 256
#define NH1  4
#define TOPK 5
#define NEDG (NN*TOPK + NN)   // 4608
#define XW   (CC+4)           // 1028
#define OUTW (NN+7)           // 775: [rel(768) | logits(2) | boxes(4) | prob(1)]
#define G1W  (NH1*HIDD)       // 1024
#define RH   128

// ---------------- device scratch (static, avoids ws_size assumptions) ---------
__device__ float g_fa[NN*HIDD];        // feats@W1_f1 + b1
__device__ float g_fb[NN*HIDD];        // feats@W1_f2
__device__ float g_x[NN*XW];           // [feats | geom]
__device__ float g_hg[NN*G1W];         // x@Wg1
__device__ float g_as1[NN*NH1], g_ad1[NN*NH1];
__device__ int   g_idx[NN*TOPK];
__device__ float g_e1[NEDG*NH1];       // e, then overwritten with exp(e-m)
__device__ float g_m1[NN*NH1], g_den1[NN*NH1];
__device__ int   g_cnt[NN], g_off[NN+1], g_cur[NN], g_inlist[NEDG];
__device__ float g_regin[NN*XW];       // [h1 | geom]
__device__ float g_h2[NN*2], g_as2[NN], g_ad2[NN], g_e2[NEDG], g_m2[NN], g_den2[NN];
__device__ float g_r1[NN*RH];

// ---------------- helpers ----------------------------------------------------
__device__ inline void edge_decode(int t, int* src, int* dst){
    if (t < NN*TOPK){ *src = t / TOPK; *dst = g_idx[t]; }
    else            { int n = t - NN*TOPK; *src = n; *dst = n; }
}

__device__ inline void atomicMaxF(float* addr, float val){
    unsigned int* ua = (unsigned int*)addr;
    unsigned int old = __float_as_uint(*addr);
    while (val > __uint_as_float(old)){
        unsigned int assumed = old;
        old = atomicCAS(ua, assumed, __float_as_uint(val));
        if (old == assumed) break;
    }
}

// ---------------- init -------------------------------------------------------
__global__ void k_init(){
    int i = blockIdx.x*blockDim.x + threadIdx.x;
    if (i < NN*NH1){ g_m1[i] = -FLT_MAX; g_den1[i] = 0.f; }
    if (i < NN){ g_cnt[i] = 0; g_cur[i] = 0; g_m2[i] = -FLT_MAX; g_den2[i] = 0.f; }
}

// x = [feats | geom]; also geom into g_regin tail cols
__global__ void k_prep(const float* __restrict__ feats, const float* __restrict__ boxes,
                       const int* __restrict__ ih, const int* __restrict__ iw){
    int i = blockIdx.x*blockDim.x + threadIdx.x;
    if (i >= NN*XW) return;
    int n = i / XW, c = i % XW;
    float v;
    if (c < CC){
        v = feats[n*CC + c];
    } else {
        float w = (float)iw[0], h = (float)ih[0];
        float x0 = boxes[n*4+0]/w, y0 = boxes[n*4+1]/h;
        float x1 = boxes[n*4+2]/w, y1 = boxes[n*4+3]/h;
        float g4[4] = {x0, y0, x1-x0, y1-y0};
        v = g4[c - CC];
        g_regin[n*XW + c] = v;
    }
    g_x[i] = v;
}

// ---------------- generic fp32 GEMM (64x64 tile, 4x4/thread) ------------------
__device__ void gemm_body(const float* __restrict__ A, const float* __restrict__ B,
                          const float* __restrict__ bias, float* __restrict__ Cm,
                          int M, int Nn, int Kd, bool relu, bool hasbias){
    __shared__ float As[16][65];
    __shared__ float Bs[16][65];
    int tx = threadIdx.x, ty = threadIdx.y;
    int t  = ty*16 + tx;
    int bm = blockIdx.y*64, bn = blockIdx.x*64;
    float acc[4][4] = {};
    for (int k0 = 0; k0 < Kd; k0 += 16){
        #pragma unroll
        for (int u = 0; u < 4; u++){
            int e  = t*4 + u;
            int mm = e >> 4, kk = e & 15;
            As[kk][mm] = (k0+kk < Kd) ? A[(size_t)(bm+mm)*Kd + k0+kk] : 0.f;
            int nn = e & 63, k2 = e >> 6;
            Bs[k2][nn] = (k0+k2 < Kd) ? B[(size_t)(k0+k2)*Nn + bn+nn] : 0.f;
        }
        __syncthreads();
        #pragma unroll
        for (int kk = 0; kk < 16; kk++){
            float a[4], b[4];
            #pragma unroll
            for (int i2 = 0; i2 < 4; i2++) a[i2] = As[kk][ty + 16*i2];
            #pragma unroll
            for (int j2 = 0; j2 < 4; j2++) b[j2] = Bs[kk][tx + 16*j2];
            #pragma unroll
            for (int i2 = 0; i2 < 4; i2++)
                #pragma unroll
                for (int j2 = 0; j2 < 4; j2++)
                    acc[i2][j2] += a[i2]*b[j2];
        }
        __syncthreads();
    }
    #pragma unroll
    for (int i2 = 0; i2 < 4; i2++){
        int row = bm + ty + 16*i2;
        #pragma unroll
        for (int j2 = 0; j2 < 4; j2++){
            int col = bn + tx + 16*j2;
            float v = acc[i2][j2];
            if (hasbias) v += bias[col];
            if (relu)    v = fmaxf(v, 0.f);
            Cm[(size_t)row*Nn + col] = v;
        }
    }
}

__global__ void k_gemm_fa(const float* feats, const float* W, const float* b1){
    gemm_body(feats, W, b1, g_fa, NN, HIDD, CC, false, true);
}
__global__ void k_gemm_fb(const float* feats, const float* W){
    gemm_body(feats, W, nullptr, g_fb, NN, HIDD, CC, false, false);
}
__global__ void k_gemm_hg(const float* W){
    gemm_body(g_x, W, nullptr, g_hg, NN, G1W, XW, false, false);
}
__global__ void k_gemm_r1(const float* W, const float* b){
    gemm_body(g_regin, W, b, g_r1, NN, RH, XW, true, true);
}

// ---------------- rel matrix -------------------------------------------------
// rel[i,j] = sum_f relu(fa[i,f]+fb[j,f]+|box_i-box_j|·W1g[:,f]) * W2r[f] + b2r
// 32x32 tile/block, 2x2 pairs/thread, f chunked by 128 in LDS.
__global__ void __launch_bounds__(256) k_rel(const float* __restrict__ boxes,
                                             const float* __restrict__ W1g,
                                             const float* __restrict__ W2r,
                                             const float* __restrict__ b2r,
                                             float* __restrict__ out){
    __shared__ float sfa[32][129];
    __shared__ float sfb[32][129];
    __shared__ float sW[4*HIDD];
    __shared__ float sWr[HIDD];
    __shared__ float sbi[32][4], sbj[32][4];
    int t  = threadIdx.x;
    int ib = blockIdx.y*32, jb = blockIdx.x*32;

    for (int e = t; e < 4*HIDD; e += 256) sW[e]  = W1g[e];
    for (int e = t; e < HIDD;   e += 256) sWr[e] = W2r[e];
    if (t < 128){ int r = t >> 2, c = t & 3; sbi[r][c] = boxes[(ib+r)*4 + c];
                                             sbj[r][c] = boxes[(jb+r)*4 + c]; }
    __syncthreads();

    int ti = t >> 4, tj = t & 15;
    float g[2][2][4];
    #pragma unroll
    for (int a = 0; a < 2; a++)
        #pragma unroll
        for (int b = 0; b < 2; b++)
            #pragma unroll
            for (int c = 0; c < 4; c++)
                g[a][b][c] = fabsf(sbi[ti+16*a][c] - sbj[tj+16*b][c]);

    float acc[2][2] = {};
    for (int fc = 0; fc < HIDD; fc += 128){
        __syncthreads();
        for (int e = t; e < 32*128; e += 256){
            int r = e >> 7, f = e & 127;
            sfa[r][f] = g_fa[(ib+r)*HIDD + fc + f];
            sfb[r][f] = g_fb[(jb+r)*HIDD + fc + f];
        }
        __syncthreads();
        for (int f = 0; f < 128; f++){
            float w0 = sW[fc+f], w1 = sW[HIDD+fc+f], w2 = sW[2*HIDD+fc+f], w3 = sW[3*HIDD+fc+f];
            float wr = sWr[fc+f];
            float fa0 = sfa[ti][f],    fa1 = sfa[ti+16][f];
            float fb0 = sfb[tj][f],    fb1 = sfb[tj+16][f];
            #pragma unroll
            for (int a = 0; a < 2; a++){
                float fav = a ? fa1 : fa0;
                #pragma unroll
                for (int b = 0; b < 2; b++){
                    float s = fav + (b ? fb1 : fb0);
                    s += g[a][b][0]*w0 + g[a][b][1]*w1 + g[a][b][2]*w2 + g[a][b][3]*w3;
                    s = fmaxf(s, 0.f);
                    acc[a][b] += s*wr;
                }
            }
        }
    }
    float bb = b2r[0];
    #pragma unroll
    for (int a = 0; a < 2; a++)
        #pragma unroll
        for (int b = 0; b < 2; b++)
            out[(size_t)(ib+ti+16*a)*OUTW + (jb+tj+16*b)] = acc[a][b] + bb;
}

// ---------------- top-K (K=5) per row, diag excluded -------------------------
__global__ void __launch_bounds__(256) k_topk(const float* __restrict__ out){
    __shared__ float sv[256]; __shared__ int si[256]; __shared__ int sel[TOPK];
    int i = blockIdx.x, t = threadIdx.x;
    const float* row = out + (size_t)i*OUTW;
    for (int k = 0; k < TOPK; k++){
        float bv = -FLT_MAX; int bj = -1;
        for (int j = t; j < NN; j += 256){
            if (j == i) continue;
            bool used = false;
            for (int u = 0; u < k; u++) if (sel[u] == j) used = true;
            if (used) continue;
            float v = row[j];
            if (v > bv){ bv = v; bj = j; }
        }
        sv[t] = bv; si[t] = bj;
        __syncthreads();
        for (int s = 128; s > 0; s >>= 1){
            if (t < s){
                float v2 = sv[t+s]; int j2 = si[t+s];
                bool better = (v2 > sv[t]) ||
                              (v2 == sv[t] && j2 >= 0 && (si[t] < 0 || j2 < si[t]));
                if (better){ sv[t] = v2; si[t] = j2; }
            }
            __syncthreads();
        }
        if (t == 0) sel[k] = si[0];
        __syncthreads();
    }
    if (t < TOPK) g_idx[i*TOPK + t] = sel[t];
}

// ---------------- CSR build --------------------------------------------------
__global__ void k_count(){
    int t = blockIdx.x*blockDim.x + threadIdx.x;
    if (t >= NEDG) return;
    int s, d; edge_decode(t, &s, &d);
    atomicAdd(&g_cnt[d], 1);
}
__global__ void k_scan(){
    if (threadIdx.x == 0 && blockIdx.x == 0){
        int s = 0;
        for (int i = 0; i < NN; i++){ g_off[i] = s; s += g_cnt[i]; }
        g_off[NN] = s;
    }
}
__global__ void k_fill(){
    int t = blockIdx.x*blockDim.x + threadIdx.x;
    if (t >= NEDG) return;
    int s, d; edge_decode(t, &s, &d);
    int pos = atomicAdd(&g_cur[d], 1);
    g_inlist[g_off[d] + pos] = t;
}

// ---------------- GAT layer 1 ------------------------------------------------
__global__ void __launch_bounds__(256) k_alpha1(const float* __restrict__ asrc,
                                                const float* __restrict__ adst){
    int n = blockIdx.x, t = threadIdx.x;
    int h = t >> 6, f0 = t & 63;
    const float* hrow = g_hg + (size_t)n*G1W + h*HIDD;
    float ss = 0.f, sd = 0.f;
    for (int u = 0; u < HIDD; u += 64){
        float hv = hrow[f0 + u];
        ss += hv * asrc[h*HIDD + f0 + u];
        sd += hv * adst[h*HIDD + f0 + u];
    }
    for (int off = 32; off; off >>= 1){
        ss += __shfl_down(ss, off);
        sd += __shfl_down(sd, off);
    }
    if (f0 == 0){ g_as1[n*NH1 + h] = ss; g_ad1[n*NH1 + h] = sd; }
}

__global__ void k_edge1a(){
    int t = blockIdx.x*blockDim.x + threadIdx.x;
    if (t >= NEDG) return;
    int s, d; edge_decode(t, &s, &d);
    #pragma unroll
    for (int h = 0; h < NH1; h++){
        float e = g_as1[s*NH1 + h] + g_ad1[d*NH1 + h];
        e = (e > 0.f) ? e : 0.2f*e;
        g_e1[t*NH1 + h] = e;
        atomicMaxF(&g_m1[d*NH1 + h], e);
    }
}
__global__ void k_edge1b(){
    int t = blockIdx.x*blockDim.x + threadIdx.x;
    if (t >= NEDG) return;
    int s, d; edge_decode(t, &s, &d);
    #pragma unroll
    for (int h = 0; h < NH1; h++){
        float ex = expf(g_e1[t*NH1 + h] - g_m1[d*NH1 + h]);
        g_e1[t*NH1 + h] = ex;
        atomicAdd(&g_den1[d*NH1 + h], ex);
    }
}

// out[n,h,f] = sum_in attn * hg[src,h,f]; +bg1; relu -> g_regin (h1 part)
__global__ void __launch_bounds__(256) k_agg1(const float* __restrict__ bg1){
    int n = blockIdx.x, t = threadIdx.x;   // t = f (256)
    int beg = g_off[n], end = g_off[n+1];
    float rden[NH1], acc[NH1] = {0.f,0.f,0.f,0.f};
    #pragma unroll
    for (int h = 0; h < NH1; h++) rden[h] = 1.f / g_den1[n*NH1 + h];
    for (int e = beg; e < end; e++){
        int eid = g_inlist[e];
        int src = (eid < NN*TOPK) ? eid / TOPK : eid - NN*TOPK;
        const float* hrow = g_hg + (size_t)src*G1W;
        #pragma unroll
        for (int h = 0; h < NH1; h++){
            float attn = g_e1[eid*NH1 + h] * rden[h];
            acc[h] += hrow[h*HIDD + t] * attn;
        }
    }
    #pragma unroll
    for (int h = 0; h < NH1; h++){
        int c = h*HIDD + t;
        float v = acc[h] + bg1[c];
        g_regin[(size_t)n*XW + c] = fmaxf(v, 0.f);
    }
}

// ---------------- GAT layer 2 ------------------------------------------------
__global__ void __launch_bounds__(128) k_h2(const float* __restrict__ Wg2,
                                            const float* __restrict__ as2w,
                                            const float* __restrict__ ad2w){
    __shared__ float s0[128], s1[128];
    int n = blockIdx.x, t = threadIdx.x;
    float a0 = 0.f, a1 = 0.f;
    for (int f = t; f < G1W; f += 128){
        float v = g_regin[(size_t)n*XW + f];
        a0 += v * Wg2[f*2 + 0];
        a1 += v * Wg2[f*2 + 1];
    }
    s0[t] = a0; s1[t] = a1; __syncthreads();
    for (int s = 64; s > 0; s >>= 1){
        if (t < s){ s0[t] += s0[t+s]; s1[t] += s1[t+s]; }
        __syncthreads();
    }
    if (t == 0){
        float h0 = s0[0], h1 = s1[0];
        g_h2[n*2+0] = h0; g_h2[n*2+1] = h1;
        g_as2[n] = h0*as2w[0] + h1*as2w[1];
        g_ad2[n] = h0*ad2w[0] + h1*ad2w[1];
    }
}

__global__ void k_edge2a(){
    int t = blockIdx.x*blockDim.x + threadIdx.x;
    if (t >= NEDG) return;
    int s, d; edge_decode(t, &s, &d);
    float e = g_as2[s] + g_ad2[d];
    e = (e > 0.f) ? e : 0.2f*e;
    g_e2[t] = e;
    atomicMaxF(&g_m2[d], e);
}
__global__ void k_edge2b(){
    int t = blockIdx.x*blockDim.x + threadIdx.x;
    if (t >= NEDG) return;
    int s, d; edge_decode(t, &s, &d);
    float ex = expf(g_e2[t] - g_m2[d]);
    g_e2[t] = ex;
    atomicAdd(&g_den2[d], ex);
}

__global__ void k_out2(const float* __restrict__ bg2, float* __restrict__ out){
    int n = blockIdx.x*blockDim.x + threadIdx.x;
    if (n >= NN) return;
    int beg = g_off[n], end = g_off[n+1];
    float l0 = 0.f, l1 = 0.f;
    float rden = 1.f / g_den2[n];
    for (int e = beg; e < end; e++){
        int eid = g_inlist[e];
        int src = (eid < NN*TOPK) ? eid / TOPK : eid - NN*TOPK;
        float attn = g_e2[eid] * rden;
        l0 += g_h2[src*2+0] * attn;
        l1 += g_h2[src*2+1] * attn;
    }
    l0 += bg2[0]; l1 += bg2[1];
    out[(size_t)n*OUTW + NN + 0] = l0;
    out[(size_t)n*OUTW + NN + 1] = l1;
    float m = fmaxf(l0, l1);
    float e0 = expf(l0 - m), e1 = expf(l1 - m);
    out[(size_t)n*OUTW + NN + 6] = e1 / (e0 + e1);
}

// ---------------- box head ---------------------------------------------------
__global__ void k_delta(const float* __restrict__ Wb2, const float* __restrict__ bb2,
                        const float* __restrict__ boxes, float* __restrict__ out){
    int n = blockIdx.x*blockDim.x + threadIdx.x;
    if (n >= NN) return;
    float d[4];
    #pragma unroll
    for (int o = 0; o < 4; o++){
        float s = bb2[o];
        for (int k = 0; k < RH; k++) s += g_r1[n*RH + k] * Wb2[k*4 + o];
        d[o] = s;
    }
    float px0 = boxes[n*4+0], py0 = boxes[n*4+1];
    float px1 = boxes[n*4+2], py1 = boxes[n*4+3];
    float pw = px1 - px0, ph = py1 - py0;
    float pcx = px0 + 0.5f*pw, pcy = py0 + 0.5f*ph;
    float gcx = d[0]*pw + pcx, gcy = d[1]*ph + pcy;
    float gw = expf(d[2])*pw,  gh = expf(d[3])*ph;
    out[(size_t)n*OUTW + NN + 2] = gcx - 0.5f*gw;
    out[(size_t)n*OUTW + NN + 3] = gcy - 0.5f*gh;
    out[(size_t)n*OUTW + NN + 4] = gcx + 0.5f*gw;
    out[(size_t)n*OUTW + NN + 5] = gcy + 0.5f*gh;
}

// ---------------- launch -----------------------------------------------------
extern "C" void kernel_launch(void* const* d_in, const int* in_sizes, int n_in,
                              void* d_out, int out_size, void* d_ws, size_t ws_size,
                              hipStream_t stream){
    const float* feats = (const float*)d_in[0];
    const float* boxes = (const float*)d_in[1];
    const int*   ih    = (const int*)  d_in[2];
    const int*   iw    = (const int*)  d_in[3];
    const float* W1f1  = (const float*)d_in[4];
    const float* W1f2  = (const float*)d_in[5];
    const float* W1g   = (const float*)d_in[6];
    const float* b1    = (const float*)d_in[7];
    const float* W2r   = (const float*)d_in[8];
    const float* b2r   = (const float*)d_in[9];
    const float* Wg1   = (const float*)d_in[10];
    const float* asrc1 = (const float*)d_in[11];
    const float* adst1 = (const float*)d_in[12];
    const float* bg1   = (const float*)d_in[13];
    const float* Wg2   = (const float*)d_in[14];
    const float* asrc2 = (const float*)d_in[15];
    const float* adst2 = (const float*)d_in[16];
    const float* bg2   = (const float*)d_in[17];
    const float* Wb1   = (const float*)d_in[18];
    const float* bb1   = (const float*)d_in[19];
    const float* Wb2   = (const float*)d_in[20];
    const float* bb2   = (const float*)d_in[21];
    float* out = (float*)d_out;

    dim3 b2d(16,16);

    k_init<<<(NN*NH1 + 255)/256, 256, 0, stream>>>();
    k_prep<<<(NN*XW + 255)/256, 256, 0, stream>>>(feats, boxes, ih, iw);

    k_gemm_fa<<<dim3(HIDD/64, NN/64), b2d, 0, stream>>>(feats, W1f1, b1);
    k_gemm_fb<<<dim3(HIDD/64, NN/64), b2d, 0, stream>>>(feats, W1f2);
    k_gemm_hg<<<dim3(G1W/64,  NN/64), b2d, 0, stream>>>(Wg1);

    k_rel<<<dim3(NN/32, NN/32), 256, 0, stream>>>(boxes, W1g, W2r, b2r, out);
    k_topk<<<NN, 256, 0, stream>>>(out);

    k_count<<<(NEDG + 255)/256, 256, 0, stream>>>();
    k_scan<<<1, 64, 0, stream>>>();
    k_fill<<<(NEDG + 255)/256, 256, 0, stream>>>();

    k_alpha1<<<NN, 256, 0, stream>>>(asrc1, adst1);
    k_edge1a<<<(NEDG + 255)/256, 256, 0, stream>>>();
    k_edge1b<<<(NEDG + 255)/256, 256, 0, stream>>>();
    k_agg1<<<NN, 256, 0, stream>>>(bg1);

    k_h2<<<NN, 128, 0, stream>>>(Wg2, asrc2, adst2);
    k_edge2a<<<(NEDG + 255)/256, 256, 0, stream>>>();
    k_edge2b<<<(NEDG + 255)/256, 256, 0, stream>>>();
    k_out2<<<(NN + 255)/256, 256, 0, stream>>>(bg2, out);

    k_gemm_r1<<<dim3(RH/64, NN/64), b2d, 0, stream>>>(Wb1, bb1);
    k_delta<<<(NN + 255)/256, 256, 0, stream>>>(Wb2, bb2, boxes, out);
}

// Round 2
// 367.092 us; speedup vs baseline: 2.0281x; 2.0281x over previous
//
#include <hip/hip_runtime.h>
#include <float.h>

#define NN   768
#define CC   1024
#define HIDD 256
#define NH1  4
#define TOPK 5
#define NEDG (NN*TOPK + NN)   // 4608
#define XW   (CC+4)           // 1028
#define OUTW (NN+7)           // 775: [rel(768) | logits(2) | boxes(4) | prob(1)]
#define G1W  (NH1*HIDD)       // 1024
#define RH   128

// ---------------- device scratch ---------------------------------------------
__device__ float g_fa[NN*HIDD];
__device__ float g_fb[NN*HIDD];
__device__ float g_x[NN*XW];
__device__ float g_hg[NN*G1W];
__device__ float g_as1[NN*NH1], g_ad1[NN*NH1];
__device__ int   g_idx[NN*TOPK];
__device__ float g_e1[NEDG*NH1];
__device__ float g_m1[NN*NH1], g_den1[NN*NH1];
__device__ int   g_cnt[NN], g_off[NN+1], g_cur[NN], g_inlist[NEDG];
__device__ float g_regin[NN*XW];
__device__ float g_h2[NN*2], g_as2[NN], g_ad2[NN], g_e2[NEDG], g_m2[NN], g_den2[NN];
__device__ float g_r1[NN*RH];

// ---------------- helpers ----------------------------------------------------
__device__ inline void edge_decode(int t, int* src, int* dst){
    if (t < NN*TOPK){ *src = t / TOPK; *dst = g_idx[t]; }
    else            { int n = t - NN*TOPK; *src = n; *dst = n; }
}

__device__ inline void atomicMaxF(float* addr, float val){
    unsigned int* ua = (unsigned int*)addr;
    unsigned int old = __float_as_uint(*addr);
    while (val > __uint_as_float(old)){
        unsigned int assumed = old;
        old = atomicCAS(ua, assumed, __float_as_uint(val));
        if (old == assumed) break;
    }
}

// ---------------- prep (+init merged) ----------------------------------------
__global__ void k_prep(const float* __restrict__ feats, const float* __restrict__ boxes,
                       const int* __restrict__ ih, const int* __restrict__ iw){
    int i = blockIdx.x*blockDim.x + threadIdx.x;
    if (i < NN*NH1){ g_m1[i] = -FLT_MAX; g_den1[i] = 0.f; }
    if (i < NN){ g_cnt[i] = 0; g_cur[i] = 0; g_m2[i] = -FLT_MAX; g_den2[i] = 0.f; }
    if (i >= NN*XW) return;
    int n = i / XW, c = i % XW;
    float v;
    if (c < CC){
        v = feats[n*CC + c];
    } else {
        float w = (float)iw[0], h = (float)ih[0];
        float x0 = boxes[n*4+0]/w, y0 = boxes[n*4+1]/h;
        float x1 = boxes[n*4+2]/w, y1 = boxes[n*4+3]/h;
        float g4[4] = {x0, y0, x1-x0, y1-y0};
        v = g4[c - CC];
        g_regin[n*XW + c] = v;
    }
    g_x[i] = v;
}

// ---------------- fp32 GEMM body: 64x64 tile, 256 thr, 4x4/thread ------------
// As/Bs stride 68 floats: 272B (16B aligned), rows shift 4 banks.
__device__ __forceinline__ void gemm64(const float* __restrict__ A,
                                       const float* __restrict__ B,
                                       const float* __restrict__ bias,
                                       float* __restrict__ C,
                                       int Nn, int K, int bm, int bn,
                                       bool relu, bool hasbias,
                                       float (*As)[68], float (*Bs)[68]){
    int t  = threadIdx.x;
    int tx = t & 15, ty = t >> 4;
    int ar = t >> 2, akq = (t & 3) * 4;       // A staging: row, k-quad
    int bkk = t >> 4, bnn = (t & 15) * 4;     // B staging: k-row, n-quad
    float acc[4][4] = {};
    for (int k0 = 0; k0 < K; k0 += 16){
        float4 av = make_float4(0.f,0.f,0.f,0.f);
        float4 bv = make_float4(0.f,0.f,0.f,0.f);
        if (k0 + akq < K) av = *(const float4*)&A[(size_t)(bm+ar)*K + k0 + akq];
        if (k0 + bkk < K) bv = *(const float4*)&B[(size_t)(k0+bkk)*Nn + bn + bnn];
        As[akq+0][ar] = av.x; As[akq+1][ar] = av.y;
        As[akq+2][ar] = av.z; As[akq+3][ar] = av.w;
        *(float4*)&Bs[bkk][bnn] = bv;
        __syncthreads();
        #pragma unroll
        for (int kk = 0; kk < 16; kk++){
            float4 a4 = *(const float4*)&As[kk][ty*4];
            float4 b4 = *(const float4*)&Bs[kk][tx*4];
            const float* aa = (const float*)&a4;
            const float* bb = (const float*)&b4;
            #pragma unroll
            for (int i = 0; i < 4; i++)
                #pragma unroll
                for (int j = 0; j < 4; j++)
                    acc[i][j] += aa[i]*bb[j];
        }
        __syncthreads();
    }
    #pragma unroll
    for (int i = 0; i < 4; i++){
        int row = bm + ty*4 + i;
        float4 o;
        float* oo = (float*)&o;
        #pragma unroll
        for (int j = 0; j < 4; j++){
            float v = acc[i][j];
            if (hasbias) v += bias[bn + tx*4 + j];
            if (relu)    v = fmaxf(v, 0.f);
            oo[j] = v;
        }
        *(float4*)&C[(size_t)row*Nn + bn + tx*4] = o;
    }
}

// fused: blocks 0..191 -> hg (x@Wg1), 192..239 -> fa, 240..287 -> fb
__global__ void __launch_bounds__(256) k_gemm_all(const float* __restrict__ feats,
                                                  const float* __restrict__ W1f1,
                                                  const float* __restrict__ W1f2,
                                                  const float* __restrict__ b1,
                                                  const float* __restrict__ Wg1){
    __shared__ float As[16][68];
    __shared__ float Bs[16][68];
    int b = blockIdx.x;
    if (b < 192){
        gemm64(g_x, Wg1, nullptr, g_hg, G1W, XW, (b>>4)*64, (b&15)*64, false, false, As, Bs);
    } else if (b < 240){
        int bb = b - 192;
        gemm64(feats, W1f1, b1, g_fa, HIDD, CC, (bb>>2)*64, (bb&3)*64, false, true, As, Bs);
    } else {
        int bb = b - 240;
        gemm64(feats, W1f2, nullptr, g_fb, HIDD, CC, (bb>>2)*64, (bb&3)*64, false, false, As, Bs);
    }
}

__global__ void __launch_bounds__(256) k_gemm_r1k(const float* __restrict__ Wb1,
                                                  const float* __restrict__ bb1){
    __shared__ float As[16][68];
    __shared__ float Bs[16][68];
    int b = blockIdx.x;
    gemm64(g_regin, Wb1, bb1, g_r1, RH, XW, (b>>1)*64, (b&1)*64, true, true, As, Bs);
}

// ---------------- rel matrix -------------------------------------------------
// rel[i,j] = sum_f relu(fa[i,f]+fb[j,f]+|box_i-box_j|·W1g[:,f]) * W2r[f] + b2r
__global__ void __launch_bounds__(256) k_rel(const float* __restrict__ boxes,
                                             const float* __restrict__ W1g,
                                             const float* __restrict__ W2r,
                                             const float* __restrict__ b2r,
                                             float* __restrict__ out){
    __shared__ float sfa[32][132];   // stride 132 floats: 528B, 16B aligned
    __shared__ float sfb[32][132];
    __shared__ float sW[4*HIDD];
    __shared__ float sWr[HIDD];
    __shared__ float sbi[32][4], sbj[32][4];
    int t  = threadIdx.x;
    int ib = blockIdx.y*32, jb = blockIdx.x*32;

    for (int e = t; e < 4*HIDD; e += 256) sW[e]  = W1g[e];
    for (int e = t; e < HIDD;   e += 256) sWr[e] = W2r[e];
    if (t < 128){ int r = t >> 2, c = t & 3; sbi[r][c] = boxes[(ib+r)*4 + c];
                                             sbj[r][c] = boxes[(jb+r)*4 + c]; }
    __syncthreads();

    int ti = t >> 4, tj = t & 15;
    float g[2][2][4];
    #pragma unroll
    for (int a = 0; a < 2; a++)
        #pragma unroll
        for (int b = 0; b < 2; b++)
            #pragma unroll
            for (int c = 0; c < 4; c++)
                g[a][b][c] = fabsf(sbi[ti+16*a][c] - sbj[tj+16*b][c]);

    float acc[2][2] = {};
    for (int fc = 0; fc < HIDD; fc += 128){
        __syncthreads();
        for (int e = t; e < 32*32; e += 256){
            int r = e >> 5, fq = (e & 31)*4;
            *(float4*)&sfa[r][fq] = *(const float4*)&g_fa[(size_t)(ib+r)*HIDD + fc + fq];
            *(float4*)&sfb[r][fq] = *(const float4*)&g_fb[(size_t)(jb+r)*HIDD + fc + fq];
        }
        __syncthreads();
        for (int f = 0; f < 128; f += 4){
            float4 w0q = *(const float4*)&sW[0*HIDD + fc + f];
            float4 w1q = *(const float4*)&sW[1*HIDD + fc + f];
            float4 w2q = *(const float4*)&sW[2*HIDD + fc + f];
            float4 w3q = *(const float4*)&sW[3*HIDD + fc + f];
            float4 wrq = *(const float4*)&sWr[fc + f];
            float4 fa0q = *(const float4*)&sfa[ti][f];
            float4 fa1q = *(const float4*)&sfa[ti+16][f];
            float4 fb0q = *(const float4*)&sfb[tj][f];
            float4 fb1q = *(const float4*)&sfb[tj+16][f];
            const float* W0 = (const float*)&w0q; const float* W1 = (const float*)&w1q;
            const float* W2 = (const float*)&w2q; const float* W3 = (const float*)&w3q;
            const float* WR = (const float*)&wrq;
            const float* FA0 = (const float*)&fa0q; const float* FA1 = (const float*)&fa1q;
            const float* FB0 = (const float*)&fb0q; const float* FB1 = (const float*)&fb1q;
            #pragma unroll
            for (int q = 0; q < 4; q++){
                float w0 = W0[q], w1 = W1[q], w2 = W2[q], w3 = W3[q], wr = WR[q];
                float fav[2] = {FA0[q], FA1[q]};
                float fbv[2] = {FB0[q], FB1[q]};
                #pragma unroll
                for (int a = 0; a < 2; a++)
                    #pragma unroll
                    for (int b = 0; b < 2; b++){
                        float s = fav[a] + fbv[b];
                        s += g[a][b][0]*w0 + g[a][b][1]*w1 + g[a][b][2]*w2 + g[a][b][3]*w3;
                        s = fmaxf(s, 0.f);
                        acc[a][b] += s*wr;
                    }
            }
        }
    }
    float bb = b2r[0];
    #pragma unroll
    for (int a = 0; a < 2; a++)
        #pragma unroll
        for (int b = 0; b < 2; b++)
            out[(size_t)(ib+ti+16*a)*OUTW + (jb+tj+16*b)] = acc[a][b] + bb;
}

// ---------------- top-K (K=5) per row, one wave per row ----------------------
__global__ void __launch_bounds__(64) k_topk(const float* __restrict__ out){
    int i = blockIdx.x, t = threadIdx.x;
    const float* row = out + (size_t)i*OUTW;
    int sel[TOPK];
    for (int k = 0; k < TOPK; k++){
        float bv = -FLT_MAX; int bj = NN;
        for (int j = t; j < NN; j += 64){
            if (j == i) continue;
            bool used = false;
            #pragma unroll
            for (int u = 0; u < TOPK; u++) if (u < k && sel[u] == j) used = true;
            if (used) continue;
            float v = row[j];
            if (v > bv || (v == bv && j < bj)){ bv = v; bj = j; }
        }
        for (int off = 32; off; off >>= 1){
            float v2 = __shfl_down(bv, off);
            int   j2 = __shfl_down(bj, off);
            if (v2 > bv || (v2 == bv && j2 < bj)){ bv = v2; bj = j2; }
        }
        bv = __shfl(bv, 0); bj = __shfl(bj, 0);
        sel[k] = bj;
    }
    if (t < TOPK) g_idx[i*TOPK + t] = sel[t];
}

// ---------------- CSR build --------------------------------------------------
__global__ void k_count(){
    int t = blockIdx.x*blockDim.x + threadIdx.x;
    if (t >= NEDG) return;
    int s, d; edge_decode(t, &s, &d);
    atomicAdd(&g_cnt[d], 1);
}
__global__ void k_scan(){
    if (threadIdx.x == 0 && blockIdx.x == 0){
        int s = 0;
        for (int i = 0; i < NN; i++){ g_off[i] = s; s += g_cnt[i]; }
        g_off[NN] = s;
    }
}
__global__ void k_fill(){
    int t = blockIdx.x*blockDim.x + threadIdx.x;
    if (t >= NEDG) return;
    int s, d; edge_decode(t, &s, &d);
    int pos = atomicAdd(&g_cur[d], 1);
    g_inlist[g_off[d] + pos] = t;
}

// ---------------- GAT layer 1 ------------------------------------------------
__global__ void __launch_bounds__(256) k_alpha1(const float* __restrict__ asrc,
                                                const float* __restrict__ adst){
    int n = blockIdx.x, t = threadIdx.x;
    int h = t >> 6, f0 = t & 63;
    const float* hrow = g_hg + (size_t)n*G1W + h*HIDD;
    float ss = 0.f, sd = 0.f;
    for (int u = 0; u < HIDD; u += 64){
        float hv = hrow[f0 + u];
        ss += hv * asrc[h*HIDD + f0 + u];
        sd += hv * adst[h*HIDD + f0 + u];
    }
    for (int off = 32; off; off >>= 1){
        ss += __shfl_down(ss, off);
        sd += __shfl_down(sd, off);
    }
    if (f0 == 0){ g_as1[n*NH1 + h] = ss; g_ad1[n*NH1 + h] = sd; }
}

__global__ void k_edge1a(){
    int t = blockIdx.x*blockDim.x + threadIdx.x;
    if (t >= NEDG) return;
    int s, d; edge_decode(t, &s, &d);
    #pragma unroll
    for (int h = 0; h < NH1; h++){
        float e = g_as1[s*NH1 + h] + g_ad1[d*NH1 + h];
        e = (e > 0.f) ? e : 0.2f*e;
        g_e1[t*NH1 + h] = e;
        atomicMaxF(&g_m1[d*NH1 + h], e);
    }
}
__global__ void k_edge1b(){
    int t = blockIdx.x*blockDim.x + threadIdx.x;
    if (t >= NEDG) return;
    int s, d; edge_decode(t, &s, &d);
    #pragma unroll
    for (int h = 0; h < NH1; h++){
        float ex = expf(g_e1[t*NH1 + h] - g_m1[d*NH1 + h]);
        g_e1[t*NH1 + h] = ex;
        atomicAdd(&g_den1[d*NH1 + h], ex);
    }
}

__global__ void __launch_bounds__(256) k_agg1(const float* __restrict__ bg1){
    int n = blockIdx.x, t = threadIdx.x;   // t = f (256)
    int beg = g_off[n], end = g_off[n+1];
    float rden[NH1], acc[NH1] = {0.f,0.f,0.f,0.f};
    #pragma unroll
    for (int h = 0; h < NH1; h++) rden[h] = 1.f / g_den1[n*NH1 + h];
    for (int e = beg; e < end; e++){
        int eid = g_inlist[e];
        int src = (eid < NN*TOPK) ? eid / TOPK : eid - NN*TOPK;
        const float* hrow = g_hg + (size_t)src*G1W;
        #pragma unroll
        for (int h = 0; h < NH1; h++){
            float attn = g_e1[eid*NH1 + h] * rden[h];
            acc[h] += hrow[h*HIDD + t] * attn;
        }
    }
    #pragma unroll
    for (int h = 0; h < NH1; h++){
        int c = h*HIDD + t;
        float v = acc[h] + bg1[c];
        g_regin[(size_t)n*XW + c] = fmaxf(v, 0.f);
    }
}

// ---------------- GAT layer 2 ------------------------------------------------
__global__ void __launch_bounds__(128) k_h2(const float* __restrict__ Wg2,
                                            const float* __restrict__ as2w,
                                            const float* __restrict__ ad2w){
    __shared__ float s0[128], s1[128];
    int n = blockIdx.x, t = threadIdx.x;
    float a0 = 0.f, a1 = 0.f;
    for (int f = t; f < G1W; f += 128){
        float v = g_regin[(size_t)n*XW + f];
        a0 += v * Wg2[f*2 + 0];
        a1 += v * Wg2[f*2 + 1];
    }
    s0[t] = a0; s1[t] = a1; __syncthreads();
    for (int s = 64; s > 0; s >>= 1){
        if (t < s){ s0[t] += s0[t+s]; s1[t] += s1[t+s]; }
        __syncthreads();
    }
    if (t == 0){
        float h0 = s0[0], h1 = s1[0];
        g_h2[n*2+0] = h0; g_h2[n*2+1] = h1;
        g_as2[n] = h0*as2w[0] + h1*as2w[1];
        g_ad2[n] = h0*ad2w[0] + h1*ad2w[1];
    }
}

__global__ void k_edge2a(){
    int t = blockIdx.x*blockDim.x + threadIdx.x;
    if (t >= NEDG) return;
    int s, d; edge_decode(t, &s, &d);
    float e = g_as2[s] + g_ad2[d];
    e = (e > 0.f) ? e : 0.2f*e;
    g_e2[t] = e;
    atomicMaxF(&g_m2[d], e);
}
__global__ void k_edge2b(){
    int t = blockIdx.x*blockDim.x + threadIdx.x;
    if (t >= NEDG) return;
    int s, d; edge_decode(t, &s, &d);
    float ex = expf(g_e2[t] - g_m2[d]);
    g_e2[t] = ex;
    atomicAdd(&g_den2[d], ex);
}

__global__ void k_out2(const float* __restrict__ bg2, float* __restrict__ out){
    int n = blockIdx.x*blockDim.x + threadIdx.x;
    if (n >= NN) return;
    int beg = g_off[n], end = g_off[n+1];
    float l0 = 0.f, l1 = 0.f;
    float rden = 1.f / g_den2[n];
    for (int e = beg; e < end; e++){
        int eid = g_inlist[e];
        int src = (eid < NN*TOPK) ? eid / TOPK : eid - NN*TOPK;
        float attn = g_e2[eid] * rden;
        l0 += g_h2[src*2+0] * attn;
        l1 += g_h2[src*2+1] * attn;
    }
    l0 += bg2[0]; l1 += bg2[1];
    out[(size_t)n*OUTW + NN + 0] = l0;
    out[(size_t)n*OUTW + NN + 1] = l1;
    float m = fmaxf(l0, l1);
    float e0 = expf(l0 - m), e1 = expf(l1 - m);
    out[(size_t)n*OUTW + NN + 6] = e1 / (e0 + e1);
}

// ---------------- box head ---------------------------------------------------
__global__ void k_delta(const float* __restrict__ Wb2, const float* __restrict__ bb2,
                        const float* __restrict__ boxes, float* __restrict__ out){
    int n = blockIdx.x*blockDim.x + threadIdx.x;
    if (n >= NN) return;
    float d[4];
    #pragma unroll
    for (int o = 0; o < 4; o++){
        float s = bb2[o];
        for (int k = 0; k < RH; k++) s += g_r1[n*RH + k] * Wb2[k*4 + o];
        d[o] = s;
    }
    float px0 = boxes[n*4+0], py0 = boxes[n*4+1];
    float px1 = boxes[n*4+2], py1 = boxes[n*4+3];
    float pw = px1 - px0, ph = py1 - py0;
    float pcx = px0 + 0.5f*pw, pcy = py0 + 0.5f*ph;
    float gcx = d[0]*pw + pcx, gcy = d[1]*ph + pcy;
    float gw = expf(d[2])*pw,  gh = expf(d[3])*ph;
    out[(size_t)n*OUTW + NN + 2] = gcx - 0.5f*gw;
    out[(size_t)n*OUTW + NN + 3] = gcy - 0.5f*gh;
    out[(size_t)n*OUTW + NN + 4] = gcx + 0.5f*gw;
    out[(size_t)n*OUTW + NN + 5] = gcy + 0.5f*gh;
}

// ---------------- launch -----------------------------------------------------
extern "C" void kernel_launch(void* const* d_in, const int* in_sizes, int n_in,
                              void* d_out, int out_size, void* d_ws, size_t ws_size,
                              hipStream_t stream){
    const float* feats = (const float*)d_in[0];
    const float* boxes = (const float*)d_in[1];
    const int*   ih    = (const int*)  d_in[2];
    const int*   iw    = (const int*)  d_in[3];
    const float* W1f1  = (const float*)d_in[4];
    const float* W1f2  = (const float*)d_in[5];
    const float* W1g   = (const float*)d_in[6];
    const float* b1    = (const float*)d_in[7];
    const float* W2r   = (const float*)d_in[8];
    const float* b2r   = (const float*)d_in[9];
    const float* Wg1   = (const float*)d_in[10];
    const float* asrc1 = (const float*)d_in[11];
    const float* adst1 = (const float*)d_in[12];
    const float* bg1   = (const float*)d_in[13];
    const float* Wg2   = (const float*)d_in[14];
    const float* asrc2 = (const float*)d_in[15];
    const float* adst2 = (const float*)d_in[16];
    const float* bg2   = (const float*)d_in[17];
    const float* Wb1   = (const float*)d_in[18];
    const float* bb1   = (const float*)d_in[19];
    const float* Wb2   = (const float*)d_in[20];
    const float* bb2   = (const float*)d_in[21];
    float* out = (float*)d_out;

    k_prep<<<(NN*XW + 255)/256, 256, 0, stream>>>(feats, boxes, ih, iw);

    k_gemm_all<<<288, 256, 0, stream>>>(feats, W1f1, W1f2, b1, Wg1);

    k_rel<<<dim3(NN/32, NN/32), 256, 0, stream>>>(boxes, W1g, W2r, b2r, out);
    k_topk<<<NN, 64, 0, stream>>>(out);

    k_count<<<(NEDG + 255)/256, 256, 0, stream>>>();
    k_scan<<<1, 64, 0, stream>>>();
    k_fill<<<(NEDG + 255)/256, 256, 0, stream>>>();

    k_alpha1<<<NN, 256, 0, stream>>>(asrc1, adst1);
    k_edge1a<<<(NEDG + 255)/256, 256, 0, stream>>>();
    k_edge1b<<<(NEDG + 255)/256, 256, 0, stream>>>();
    k_agg1<<<NN, 256, 0, stream>>>(bg1);

    k_h2<<<NN, 128, 0, stream>>>(Wg2, asrc2, adst2);
    k_edge2a<<<(NEDG + 255)/256, 256, 0, stream>>>();
    k_edge2b<<<(NEDG + 255)/256, 256, 0, stream>>>();
    k_out2<<<(NN + 255)/256, 256, 0, stream>>>(bg2, out);

    k_gemm_r1k<<<24, 256, 0, stream>>>(Wb1, bb1);
    k_delta<<<(NN + 255)/256, 256, 0, stream>>>(Wb2, bb2, boxes, out);
}

// Round 3
// 177.241 us; speedup vs baseline: 4.2006x; 2.0711x over previous
//
#include <hip/hip_runtime.h>
#include <float.h>

#define NN   768
#define CC   1024
#define HIDD 256
#define NH1  4
#define TOPK 5
#define NEDG (NN*TOPK + NN)   // 4608
#define XW   (CC+4)           // 1028
#define KP   1056             // padded K (33*32)
#define OUTW (NN+7)           // 775
#define G1W  (NH1*HIDD)       // 1024
#define RH   128

typedef __attribute__((ext_vector_type(8))) short short8;
typedef __attribute__((ext_vector_type(4))) float f32x4;

// ---------------- device scratch ---------------------------------------------
__device__ unsigned short g_featsb[NN*CC];     // bf16 feats
__device__ unsigned short g_xb[NN*KP];         // bf16 [feats|geom|0pad]
__device__ unsigned short g_wg1t[G1W*KP];      // bf16 Wg1^T  [n][k]
__device__ unsigned short g_w1f1t[HIDD*CC];    // bf16 W1f1^T
__device__ unsigned short g_w1f2t[HIDD*CC];    // bf16 W1f2^T
__device__ unsigned short g_wb1t[RH*KP];       // bf16 Wb1^T
__device__ unsigned short g_reginb[NN*KP];     // bf16 [h1|geom|0pad]
__device__ float g_fa[NN*HIDD];
__device__ float g_fb[NN*HIDD];
__device__ float g_hg[NN*G1W];
__device__ float g_as1[NN*NH1], g_ad1[NN*NH1];
__device__ int   g_idx[NN*TOPK];
__device__ int   g_off[NN+1], g_inlist[NEDG];
__device__ float g_h2[NN*2], g_as2[NN], g_ad2[NN];
__device__ float g_r1[NN*RH];

// ---------------- helpers ----------------------------------------------------
__device__ __forceinline__ unsigned short f2bf(float f){
    unsigned int u = __float_as_uint(f);
    unsigned int r = (u + 0x7FFFu + ((u >> 16) & 1u)) >> 16;
    return (unsigned short)r;
}
__device__ __forceinline__ int edge_src(int eid){
    return (eid < NN*TOPK) ? (eid / TOPK) : (eid - NN*TOPK);
}

// ---------------- prep: bf16 conversions of activations ----------------------
__global__ void k_prep(const float* __restrict__ feats, const float* __restrict__ boxes,
                       const int* __restrict__ ih, const int* __restrict__ iw){
    int i = blockIdx.x*blockDim.x + threadIdx.x;
    if (i >= NN*KP) return;
    int n = i / KP, c = i % KP;
    float v = 0.f;
    if (c < CC){
        v = feats[n*CC + c];
        unsigned short b = f2bf(v);
        g_xb[i] = b;
        g_featsb[n*CC + c] = b;
    } else {
        if (c < CC+4){
            float w = (float)iw[0], h = (float)ih[0];
            float x0 = boxes[n*4+0]/w, y0 = boxes[n*4+1]/h;
            float x1 = boxes[n*4+2]/w, y1 = boxes[n*4+3]/h;
            float g4[4] = {x0, y0, x1-x0, y1-y0};
            v = g4[c - CC];
        }
        unsigned short b = f2bf(v);
        g_xb[i] = b;
        g_reginb[i] = b;   // geom tail + zero pad of regin
    }
}

// ---------------- weight transpose + bf16 convert ----------------------------
__device__ __forceinline__ void tconv(const float* __restrict__ W, int Kin, int N, int Kpad,
                                      unsigned short* __restrict__ O, int k0, int n0,
                                      float (*tile)[33]){
    int tx = threadIdx.x, ty = threadIdx.y;
    #pragma unroll
    for (int i = 0; i < 4; i++){
        int k = k0 + ty + 8*i;
        tile[ty+8*i][tx] = (k < Kin) ? W[(size_t)k*N + n0 + tx] : 0.f;
    }
    __syncthreads();
    #pragma unroll
    for (int i = 0; i < 4; i++){
        int n = n0 + ty + 8*i;
        O[(size_t)n*Kpad + k0 + tx] = f2bf(tile[tx][ty+8*i]);
    }
}

__global__ void __launch_bounds__(256) k_wconv(const float* __restrict__ Wg1,
                                               const float* __restrict__ W1f1,
                                               const float* __restrict__ W1f2,
                                               const float* __restrict__ Wb1){
    __shared__ float tile[32][33];
    int b = blockIdx.x;
    if (b < 1056){                       // Wg1: 1028x1024 -> [1024][1056]
        int kt = b % 33, nt = b / 33;
        tconv(Wg1, XW, G1W, KP, g_wg1t, kt*32, nt*32, tile);
    } else if (b < 1312){                // W1f1: 1024x256 -> [256][1024]
        int bb = b - 1056;
        int kt = bb % 32, nt = bb / 32;
        tconv(W1f1, CC, HIDD, CC, g_w1f1t, kt*32, nt*32, tile);
    } else if (b < 1568){                // W1f2
        int bb = b - 1312;
        int kt = bb % 32, nt = bb / 32;
        tconv(W1f2, CC, HIDD, CC, g_w1f2t, kt*32, nt*32, tile);
    } else {                             // Wb1: 1028x128 -> [128][1056]
        int bb = b - 1568;
        int kt = bb % 33, nt = bb / 33;
        tconv(Wb1, XW, RH, KP, g_wb1t, kt*32, nt*32, tile);
    }
}

// ---------------- MFMA bf16 GEMM: 64x64 tile, 4 waves, 32x32/wave ------------
// A [M][lda] bf16 row-major; Bt [N][ldb] bf16 (= B^T); C fp32 [M][ldc].
#define LSTR 40   // LDS row stride in shorts (80B: 16B-aligned, ~conflict-free)
__device__ __forceinline__ void mfma_gemm64(const unsigned short* __restrict__ A, int lda,
                                            const unsigned short* __restrict__ Bt, int ldb,
                                            int Ks, float* __restrict__ C, int ldc,
                                            const float* __restrict__ bias, bool relu,
                                            int bm, int bn,
                                            unsigned short* As, unsigned short* Bs){
    const int t = threadIdx.x;
    const int l = t & 63, w = t >> 6;
    const int wr = w >> 1, wc = w & 1;
    const int sr = t >> 2, sq = (t & 3) * 8;         // staging row / k-offset(shorts)
    const size_t aoff = (size_t)(bm + sr)*lda + sq;
    const size_t boff = (size_t)(bn + sr)*ldb + sq;

    f32x4 acc[2][2];
    #pragma unroll
    for (int i = 0; i < 2; i++)
        #pragma unroll
        for (int j = 0; j < 2; j++)
            acc[i][j] = (f32x4){0.f,0.f,0.f,0.f};

    const int arow0 = (wr*32 + (l & 15)) * LSTR + ((l >> 4) * 8);
    const int brow0 = (wc*32 + (l & 15)) * LSTR + ((l >> 4) * 8);

    float4 a0v, b0v, a1v, b1v;
    a0v = *(const float4*)&A[aoff];            b0v = *(const float4*)&Bt[boff];
    a1v = *(const float4*)&A[aoff + 32];       b1v = *(const float4*)&Bt[boff + 32];

    for (int s = 0; s < Ks; s += 2){
        // ---- even step: buffer 0
        *(float4*)&As[sr*LSTR + sq] = a0v;
        *(float4*)&Bs[sr*LSTR + sq] = b0v;
        if (s + 2 < Ks){
            a0v = *(const float4*)&A[aoff + (size_t)(s+2)*32];
            b0v = *(const float4*)&Bt[boff + (size_t)(s+2)*32];
        }
        __syncthreads();
        {
            short8 fa0 = *(const short8*)&As[arow0];
            short8 fa1 = *(const short8*)&As[arow0 + 16*LSTR];
            short8 fb0 = *(const short8*)&Bs[brow0];
            short8 fb1 = *(const short8*)&Bs[brow0 + 16*LSTR];
            acc[0][0] = __builtin_amdgcn_mfma_f32_16x16x32_bf16(fa0, fb0, acc[0][0], 0, 0, 0);
            acc[0][1] = __builtin_amdgcn_mfma_f32_16x16x32_bf16(fa0, fb1, acc[0][1], 0, 0, 0);
            acc[1][0] = __builtin_amdgcn_mfma_f32_16x16x32_bf16(fa1, fb0, acc[1][0], 0, 0, 0);
            acc[1][1] = __builtin_amdgcn_mfma_f32_16x16x32_bf16(fa1, fb1, acc[1][1], 0, 0, 0);
        }
        __syncthreads();
        if (s + 1 >= Ks) break;
        // ---- odd step: buffer 1 (second half of As/Bs)
        *(float4*)&As[64*LSTR + sr*LSTR + sq] = a1v;
        *(float4*)&Bs[64*LSTR + sr*LSTR + sq] = b1v;
        if (s + 3 < Ks){
            a1v = *(const float4*)&A[aoff + (size_t)(s+3)*32];
            b1v = *(const float4*)&Bt[boff + (size_t)(s+3)*32];
        }
        __syncthreads();
        {
            short8 fa0 = *(const short8*)&As[64*LSTR + arow0];
            short8 fa1 = *(const short8*)&As[64*LSTR + arow0 + 16*LSTR];
            short8 fb0 = *(const short8*)&Bs[64*LSTR + brow0];
            short8 fb1 = *(const short8*)&Bs[64*LSTR + brow0 + 16*LSTR];
            acc[0][0] = __builtin_amdgcn_mfma_f32_16x16x32_bf16(fa0, fb0, acc[0][0], 0, 0, 0);
            acc[0][1] = __builtin_amdgcn_mfma_f32_16x16x32_bf16(fa0, fb1, acc[0][1], 0, 0, 0);
            acc[1][0] = __builtin_amdgcn_mfma_f32_16x16x32_bf16(fa1, fb0, acc[1][0], 0, 0, 0);
            acc[1][1] = __builtin_amdgcn_mfma_f32_16x16x32_bf16(fa1, fb1, acc[1][1], 0, 0, 0);
        }
        __syncthreads();
    }

    // epilogue: C row = bm+wr*32+mi*16+(l>>4)*4+r, col = bn+wc*32+nj*16+(l&15)
    #pragma unroll
    for (int mi = 0; mi < 2; mi++){
        #pragma unroll
        for (int nj = 0; nj < 2; nj++){
            int col = bn + wc*32 + nj*16 + (l & 15);
            float bv = bias ? bias[col] : 0.f;
            #pragma unroll
            for (int r = 0; r < 4; r++){
                int row = bm + wr*32 + mi*16 + ((l >> 4) * 4) + r;
                float v = acc[mi][nj][r] + bv;
                if (relu) v = fmaxf(v, 0.f);
                C[(size_t)row*ldc + col] = v;
            }
        }
    }
}

// blocks 0..191 hg (x@Wg1), 192..239 fa, 240..287 fb
__global__ void __launch_bounds__(256) k_gemm_all(const float* __restrict__ b1){
    __shared__ unsigned short As[2*64*LSTR];
    __shared__ unsigned short Bs[2*64*LSTR];
    int b = blockIdx.x;
    if (b < 192){
        mfma_gemm64(g_xb, KP, g_wg1t, KP, 33, g_hg, G1W, nullptr, false,
                    (b>>4)*64, (b&15)*64, As, Bs);
    } else if (b < 240){
        int bb = b - 192;
        mfma_gemm64(g_featsb, CC, g_w1f1t, CC, 32, g_fa, HIDD, b1, false,
                    (bb>>2)*64, (bb&3)*64, As, Bs);
    } else {
        int bb = b - 240;
        mfma_gemm64(g_featsb, CC, g_w1f2t, CC, 32, g_fb, HIDD, nullptr, false,
                    (bb>>2)*64, (bb&3)*64, As, Bs);
    }
}

__global__ void __launch_bounds__(256) k_gemm_r1(const float* __restrict__ bb1){
    __shared__ unsigned short As[2*64*LSTR];
    __shared__ unsigned short Bs[2*64*LSTR];
    int b = blockIdx.x;
    mfma_gemm64(g_reginb, KP, g_wb1t, KP, 33, g_r1, RH, bb1, true,
                (b>>1)*64, (b&1)*64, As, Bs);
}

// ---------------- rel matrix (fp32 VALU) -------------------------------------
__global__ void __launch_bounds__(256) k_rel(const float* __restrict__ boxes,
                                             const float* __restrict__ W1g,
                                             const float* __restrict__ W2r,
                                             const float* __restrict__ b2r,
                                             float* __restrict__ out){
    __shared__ float sfa[32][132];
    __shared__ float sfb[32][132];
    __shared__ float sW[4*HIDD];
    __shared__ float sWr[HIDD];
    __shared__ float sbi[32][4], sbj[32][4];
    int t  = threadIdx.x;
    int ib = blockIdx.y*32, jb = blockIdx.x*32;

    for (int e = t; e < 4*HIDD; e += 256) sW[e]  = W1g[e];
    for (int e = t; e < HIDD;   e += 256) sWr[e] = W2r[e];
    if (t < 128){ int r = t >> 2, c = t & 3; sbi[r][c] = boxes[(ib+r)*4 + c];
                                             sbj[r][c] = boxes[(jb+r)*4 + c]; }
    __syncthreads();

    int ti = t >> 4, tj = t & 15;
    float g[2][2][4];
    #pragma unroll
    for (int a = 0; a < 2; a++)
        #pragma unroll
        for (int b = 0; b < 2; b++)
            #pragma unroll
            for (int c = 0; c < 4; c++)
                g[a][b][c] = fabsf(sbi[ti+16*a][c] - sbj[tj+16*b][c]);

    float acc[2][2] = {};
    for (int fc = 0; fc < HIDD; fc += 128){
        __syncthreads();
        for (int e = t; e < 32*32; e += 256){
            int r = e >> 5, fq = (e & 31)*4;
            *(float4*)&sfa[r][fq] = *(const float4*)&g_fa[(size_t)(ib+r)*HIDD + fc + fq];
            *(float4*)&sfb[r][fq] = *(const float4*)&g_fb[(size_t)(jb+r)*HIDD + fc + fq];
        }
        __syncthreads();
        for (int f = 0; f < 128; f += 4){
            float4 w0q = *(const float4*)&sW[0*HIDD + fc + f];
            float4 w1q = *(const float4*)&sW[1*HIDD + fc + f];
            float4 w2q = *(const float4*)&sW[2*HIDD + fc + f];
            float4 w3q = *(const float4*)&sW[3*HIDD + fc + f];
            float4 wrq = *(const float4*)&sWr[fc + f];
            float4 fa0q = *(const float4*)&sfa[ti][f];
            float4 fa1q = *(const float4*)&sfa[ti+16][f];
            float4 fb0q = *(const float4*)&sfb[tj][f];
            float4 fb1q = *(const float4*)&sfb[tj+16][f];
            const float* W0 = (const float*)&w0q; const float* W1 = (const float*)&w1q;
            const float* W2 = (const float*)&w2q; const float* W3 = (const float*)&w3q;
            const float* WR = (const float*)&wrq;
            const float* FA0 = (const float*)&fa0q; const float* FA1 = (const float*)&fa1q;
            const float* FB0 = (const float*)&fb0q; const float* FB1 = (const float*)&fb1q;
            #pragma unroll
            for (int q = 0; q < 4; q++){
                float w0 = W0[q], w1 = W1[q], w2 = W2[q], w3 = W3[q], wr = WR[q];
                float fav[2] = {FA0[q], FA1[q]};
                float fbv[2] = {FB0[q], FB1[q]};
                #pragma unroll
                for (int a = 0; a < 2; a++)
                    #pragma unroll
                    for (int b = 0; b < 2; b++){
                        float s = fav[a] + fbv[b];
                        s += g[a][b][0]*w0 + g[a][b][1]*w1 + g[a][b][2]*w2 + g[a][b][3]*w3;
                        s = fmaxf(s, 0.f);
                        acc[a][b] += s*wr;
                    }
            }
        }
    }
    float bb = b2r[0];
    #pragma unroll
    for (int a = 0; a < 2; a++)
        #pragma unroll
        for (int b = 0; b < 2; b++)
            out[(size_t)(ib+ti+16*a)*OUTW + (jb+tj+16*b)] = acc[a][b] + bb;
}

// ---------------- top-K per row ----------------------------------------------
__global__ void __launch_bounds__(64) k_topk(const float* __restrict__ out){
    int i = blockIdx.x, t = threadIdx.x;
    const float* row = out + (size_t)i*OUTW;
    int sel[TOPK];
    for (int k = 0; k < TOPK; k++){
        float bv = -FLT_MAX; int bj = NN;
        for (int j = t; j < NN; j += 64){
            if (j == i) continue;
            bool used = false;
            #pragma unroll
            for (int u = 0; u < TOPK; u++) if (u < k && sel[u] == j) used = true;
            if (used) continue;
            float v = row[j];
            if (v > bv || (v == bv && j < bj)){ bv = v; bj = j; }
        }
        for (int off = 32; off; off >>= 1){
            float v2 = __shfl_down(bv, off);
            int   j2 = __shfl_down(bj, off);
            if (v2 > bv || (v2 == bv && j2 < bj)){ bv = v2; bj = j2; }
        }
        bv = __shfl(bv, 0); bj = __shfl(bj, 0);
        sel[k] = bj;
    }
    if (t < TOPK) g_idx[i*TOPK + t] = sel[t];
}

// ---------------- CSR build: count+scan+fill in one block --------------------
__global__ void __launch_bounds__(1024) k_csr(){
    __shared__ int sa[NN], sb[NN];
    int t = threadIdx.x;
    for (int i = t; i < NN; i += 1024) sa[i] = 0;
    __syncthreads();
    for (int e = t; e < NEDG; e += 1024){
        int d = (e < NN*TOPK) ? g_idx[e] : (e - NN*TOPK);
        atomicAdd(&sa[d], 1);
    }
    __syncthreads();
    int* src = sa; int* dst = sb;
    for (int off = 1; off < NN; off <<= 1){
        for (int i = t; i < NN; i += 1024)
            dst[i] = src[i] + ((i >= off) ? src[i-off] : 0);
        __syncthreads();
        int* tmp = src; src = dst; dst = tmp;
    }
    // src = inclusive scan
    for (int i = t; i < NN; i += 1024) g_off[i] = (i ? src[i-1] : 0);
    if (t == 0) g_off[NN] = src[NN-1];
    for (int i = t; i < NN; i += 1024) dst[i] = 0;   // dst reused as cursors
    __syncthreads();
    for (int e = t; e < NEDG; e += 1024){
        int d = (e < NN*TOPK) ? g_idx[e] : (e - NN*TOPK);
        int pos = atomicAdd(&dst[d], 1);
        int base = d ? src[d-1] : 0;
        g_inlist[base + pos] = e;
    }
}

// ---------------- alpha1: per-node attention dots ----------------------------
__global__ void __launch_bounds__(256) k_alpha1(const float* __restrict__ asrc,
                                                const float* __restrict__ adst){
    int n = blockIdx.x, t = threadIdx.x;
    int h = t >> 6, f0 = t & 63;
    const float* hrow = g_hg + (size_t)n*G1W + h*HIDD;
    float ss = 0.f, sd = 0.f;
    for (int u = 0; u < HIDD; u += 64){
        float hv = hrow[f0 + u];
        ss += hv * asrc[h*HIDD + f0 + u];
        sd += hv * adst[h*HIDD + f0 + u];
    }
    for (int off = 32; off; off >>= 1){
        ss += __shfl_down(ss, off);
        sd += __shfl_down(sd, off);
    }
    if (f0 == 0){ g_as1[n*NH1 + h] = ss; g_ad1[n*NH1 + h] = sd; }
}

// ---------------- GAT1 fused: softmax + aggregate + h2 -----------------------
__global__ void __launch_bounds__(256) k_gat1(const float* __restrict__ bg1,
                                              const float* __restrict__ Wg2,
                                              const float* __restrict__ as2w,
                                              const float* __restrict__ ad2w){
    __shared__ float sattn[NN*4];    // per-edge exp values (deg<=768), [e][h]
    __shared__ float sden[4];
    __shared__ float sp0[4], sp1[4];
    int n = blockIdx.x, t = threadIdx.x;
    int beg = g_off[n], deg = g_off[n+1] - beg;
    int w = t >> 6, l = t & 63;

    // phase 1: wave w = head w computes exp(e) and its sum
    {
        float adn = g_ad1[n*NH1 + w];
        float s = 0.f;
        for (int e = l; e < deg; e += 64){
            int src = edge_src(g_inlist[beg + e]);
            float ev = g_as1[src*NH1 + w] + adn;
            ev = (ev > 0.f) ? ev : 0.2f*ev;
            float ex = expf(ev);
            sattn[e*4 + w] = ex;
            s += ex;
        }
        for (int off = 32; off; off >>= 1) s += __shfl_down(s, off);
        if (l == 0) sden[w] = s;
    }
    __syncthreads();

    // phase 2: thread t = feature f; aggregate raw, divide at end
    float rd[NH1];
    #pragma unroll
    for (int h = 0; h < NH1; h++) rd[h] = 1.f / sden[h];
    float acc[NH1] = {0.f,0.f,0.f,0.f};
    for (int e = 0; e < deg; e++){
        int src = edge_src(g_inlist[beg + e]);
        const float* hr = g_hg + (size_t)src*G1W;
        #pragma unroll
        for (int h = 0; h < NH1; h++)
            acc[h] += sattn[e*4 + h] * hr[h*HIDD + t];
    }
    float p0 = 0.f, p1 = 0.f;
    #pragma unroll
    for (int h = 0; h < NH1; h++){
        int c = h*HIDD + t;
        float v = acc[h]*rd[h] + bg1[c];
        v = fmaxf(v, 0.f);
        g_reginb[(size_t)n*KP + c] = f2bf(v);
        p0 += v * Wg2[c*2 + 0];
        p1 += v * Wg2[c*2 + 1];
    }
    // block reduce p0,p1
    for (int off = 32; off; off >>= 1){
        p0 += __shfl_down(p0, off);
        p1 += __shfl_down(p1, off);
    }
    if (l == 0){ sp0[w] = p0; sp1[w] = p1; }
    __syncthreads();
    if (t == 0){
        float h0 = sp0[0]+sp0[1]+sp0[2]+sp0[3];
        float h1 = sp1[0]+sp1[1]+sp1[2]+sp1[3];
        g_h2[n*2+0] = h0; g_h2[n*2+1] = h1;
        g_as2[n] = h0*as2w[0] + h1*as2w[1];
        g_ad2[n] = h0*ad2w[0] + h1*ad2w[1];
    }
}

// ---------------- GAT2 fused: thread per node --------------------------------
__global__ void __launch_bounds__(256) k_gat2(const float* __restrict__ bg2,
                                              float* __restrict__ out){
    int n = blockIdx.x*blockDim.x + threadIdx.x;
    if (n >= NN) return;
    int beg = g_off[n], end = g_off[n+1];
    float adn = g_ad2[n];
    float den = 0.f, l0 = 0.f, l1 = 0.f;
    for (int e = beg; e < end; e++){
        int src = edge_src(g_inlist[e]);
        float ev = g_as2[src] + adn;
        ev = (ev > 0.f) ? ev : 0.2f*ev;
        float ex = expf(ev);
        den += ex;
        l0 += ex * g_h2[src*2+0];
        l1 += ex * g_h2[src*2+1];
    }
    float rd = 1.f / den;
    l0 = l0*rd + bg2[0];
    l1 = l1*rd + bg2[1];
    out[(size_t)n*OUTW + NN + 0] = l0;
    out[(size_t)n*OUTW + NN + 1] = l1;
    float m = fmaxf(l0, l1);
    float e0 = expf(l0 - m), e1 = expf(l1 - m);
    out[(size_t)n*OUTW + NN + 6] = e1 / (e0 + e1);
}

// ---------------- box head ---------------------------------------------------
__global__ void __launch_bounds__(256) k_delta(const float* __restrict__ Wb2,
                                               const float* __restrict__ bb2,
                                               const float* __restrict__ boxes,
                                               float* __restrict__ out){
    int n = blockIdx.x*blockDim.x + threadIdx.x;
    if (n >= NN) return;
    float d[4];
    #pragma unroll
    for (int o = 0; o < 4; o++) d[o] = bb2[o];
    for (int k = 0; k < RH; k++){
        float r = g_r1[n*RH + k];
        #pragma unroll
        for (int o = 0; o < 4; o++) d[o] += r * Wb2[k*4 + o];
    }
    float px0 = boxes[n*4+0], py0 = boxes[n*4+1];
    float px1 = boxes[n*4+2], py1 = boxes[n*4+3];
    float pw = px1 - px0, ph = py1 - py0;
    float pcx = px0 + 0.5f*pw, pcy = py0 + 0.5f*ph;
    float gcx = d[0]*pw + pcx, gcy = d[1]*ph + pcy;
    float gw = expf(d[2])*pw,  gh = expf(d[3])*ph;
    out[(size_t)n*OUTW + NN + 2] = gcx - 0.5f*gw;
    out[(size_t)n*OUTW + NN + 3] = gcy - 0.5f*gh;
    out[(size_t)n*OUTW + NN + 4] = gcx + 0.5f*gw;
    out[(size_t)n*OUTW + NN + 5] = gcy + 0.5f*gh;
}

// ---------------- launch -----------------------------------------------------
extern "C" void kernel_launch(void* const* d_in, const int* in_sizes, int n_in,
                              void* d_out, int out_size, void* d_ws, size_t ws_size,
                              hipStream_t stream){
    const float* feats = (const float*)d_in[0];
    const float* boxes = (const float*)d_in[1];
    const int*   ih    = (const int*)  d_in[2];
    const int*   iw    = (const int*)  d_in[3];
    const float* W1f1  = (const float*)d_in[4];
    const float* W1f2  = (const float*)d_in[5];
    const float* W1g   = (const float*)d_in[6];
    const float* b1    = (const float*)d_in[7];
    const float* W2r   = (const float*)d_in[8];
    const float* b2r   = (const float*)d_in[9];
    const float* Wg1   = (const float*)d_in[10];
    const float* asrc1 = (const float*)d_in[11];
    const float* adst1 = (const float*)d_in[12];
    const float* bg1   = (const float*)d_in[13];
    const float* Wg2   = (const float*)d_in[14];
    const float* asrc2 = (const float*)d_in[15];
    const float* adst2 = (const float*)d_in[16];
    const float* bg2   = (const float*)d_in[17];
    const float* Wb1   = (const float*)d_in[18];
    const float* bb1   = (const float*)d_in[19];
    const float* Wb2   = (const float*)d_in[20];
    const float* bb2   = (const float*)d_in[21];
    float* out = (float*)d_out;

    k_prep<<<(NN*KP + 255)/256, 256, 0, stream>>>(feats, boxes, ih, iw);
    k_wconv<<<1700, dim3(32,8), 0, stream>>>(Wg1, W1f1, W1f2, Wb1);

    k_gemm_all<<<288, 256, 0, stream>>>(b1);

    k_rel<<<dim3(NN/32, NN/32), 256, 0, stream>>>(boxes, W1g, W2r, b2r, out);
    k_topk<<<NN, 64, 0, stream>>>(out);
    k_csr<<<1, 1024, 0, stream>>>();

    k_alpha1<<<NN, 256, 0, stream>>>(asrc1, adst1);
    k_gat1<<<NN, 256, 0, stream>>>(bg1, Wg2, asrc2, adst2);
    k_gat2<<<(NN + 255)/256, 256, 0, stream>>>(bg2, out);

    k_gemm_r1<<<24, 256, 0, stream>>>(bb1);
    k_delta<<<(NN + 255)/256, 256, 0, stream>>>(Wb2, bb2, boxes, out);
}